// Round 4
// baseline (89.963 us; speedup 1.0000x reference)
//
#include <hip/hip_runtime.h>
#include <math.h>

#define PH 7
#define PW 7
#define BB 4
#define HH 64
#define WW 64
#define CC 256
#define RR 128
#define CH4 (CC / 4)                   // 64 float4 per pixel
#define BINS_PER_IMG (RR * PH * PW)    // 6272
#define NBINS (BB * BINS_PER_IMG)      // 25088
#define NBLK (NBINS / 4)               // 6272 blocks, 4 waves each
#define BLK_PER_IMG (NBLK / 8)         // 784 per xcd slot
#define DEPTH 16                       // loads in flight per round

typedef float f4 __attribute__((ext_vector_type(4)));

__device__ __forceinline__ f4 max4(f4 a, f4 b) {
    f4 r;
    r.x = fmaxf(a.x, b.x); r.y = fmaxf(a.y, b.y);
    r.z = fmaxf(a.z, b.z); r.w = fmaxf(a.w, b.w);
    return r;
}

__device__ __forceinline__ int rfl(int x) {
    return __builtin_amdgcn_readfirstlane(x);
}

// One wave per output bin. All bin/pixel index math forced SCALAR via
// readfirstlane (lanes differ only in channel): ROI fetch -> s_load, pixel
// offset -> SGPR, each load -> global_load_dwordx4 with SGPR base + constant
// lane voffset. Zero per-load VGPR address cost => true 16-deep load pipeline
// (typical bin npix~15 = ONE latency exposure). Clamp-dups in last chunk hit
// L1 (same line). XCD swizzle: image b -> xcds {2b,2b+1} (R2/R3 evidence:
// FETCH 50->12MB). launch_bounds(256,4): cap 128 VGPR, ~6 waves/SIMD.
__global__ __launch_bounds__(256, 4) void ROIPoolingLayer_62079457296467_kernel(
    const float* __restrict__ fm, const float* __restrict__ rois,
    float* __restrict__ out)
{
    const int lane = threadIdx.x & 63;
    const int wave = rfl(threadIdx.x >> 6);       // wave-uniform from here on

    // ---- XCD swizzle: 6272 blocks = 8 xcds x 784; image b -> xcds {2b,2b+1}
    const int bid   = blockIdx.x;
    const int xcd   = bid & 7;
    const int slot  = bid >> 3;                      // 0..783
    const int b     = xcd >> 1;                      // image 0..3
    const int blkin = (xcd & 1) * BLK_PER_IMG + slot;
    const int local = blkin * 4 + wave;              // 0..6271 = r*49 + bin
    const int r     = local / (PH * PW);
    const int bin   = local - r * (PH * PW);
    const int ph    = bin / PW;
    const int pw    = bin - ph * PW;
    const int br    = b * RR + r;

    // ---- ROI decode (reference fp32 semantics, truncating casts) ----
    const f4 roi = ((const f4*)rois)[br];            // uniform addr -> s_load
    const int h0 = rfl((int)floorf((float)HH * roi.x));
    const int w0 = rfl((int)floorf((float)WW * roi.y));
    const int h1 = rfl((int)floorf((float)HH * roi.z));
    const int w1 = rfl((int)floorf((float)WW * roi.w));
    const int rh = h1 - h0;
    const int rw = w1 - w0;
    const int hstep = max(rh / PH, 1);
    const int wstep = max(rw / PW, 1);

    // Bin window [hs,he) x [ws,we); last bin extends to region end.
    int hs = h0 + ph * hstep;
    int he = (ph == PH - 1) ? (h0 + rh) : (hs + hstep);
    he = min(he, h0 + rh);  he = min(he, HH);
    int ws = w0 + pw * wstep;
    int we = (pw == PW - 1) ? (w0 + rw) : (ws + wstep);
    we = min(we, w0 + rw);  we = min(we, WW);

    const int hbin = he - hs;
    const int wbin = we - ws;
    const int npix = hbin * wbin;                    // 1..~121, typ ~15

    const f4* __restrict__ fmb =
        (const f4*)fm + ((size_t)b * HH + hs) * (WW * CH4) + (size_t)ws * CH4 + lane;

    f4 acc = (f4){-INFINITY, -INFINITY, -INFINITY, -INFINITY};

    if (npix > 0) {
        // magic divide by wbin: q = (p*m)>>16 == p/wbin, exact for p*e < 2^16
        // (p <= 120, e = m*wbin - 2^16 < wbin <= ~11)
        const unsigned m = (65536u + (unsigned)wbin - 1) / (unsigned)wbin;
        for (int p = 0; p < npix; p += DEPTH) {
            f4 v[DEPTH];
#pragma unroll
            for (int k = 0; k < DEPTH; ++k) {
                const int pk  = min(p + k, npix - 1);            // clamp: dup ok
                const int q   = (int)(((unsigned)pk * m) >> 16); // row in bin
                const int w   = pk - q * wbin;                   // col in bin
                const int off = rfl(q * WW + w);                 // SGPR offset
                v[k] = fmb[(size_t)off * CH4];
            }
            // tree reduction to shorten the dependent max chain
#pragma unroll
            for (int k = 0; k < DEPTH / 2; ++k) v[k] = max4(v[k], v[k + DEPTH / 2]);
#pragma unroll
            for (int k = 0; k < DEPTH / 4; ++k) v[k] = max4(v[k], v[k + DEPTH / 4]);
#pragma unroll
            for (int k = 0; k < DEPTH / 8; ++k) v[k] = max4(v[k], v[k + DEPTH / 8]);
            acc = max4(acc, max4(v[0], v[1]));
        }
    }

    // Output (b,r,ph,pw,C): gbin = b*6272 + local; non-temporal (never re-read).
    const size_t gbin = (size_t)b * BINS_PER_IMG + local;
    __builtin_nontemporal_store(acc, (f4*)out + gbin * CH4 + lane);
}

extern "C" void kernel_launch(void* const* d_in, const int* in_sizes, int n_in,
                              void* d_out, int out_size, void* d_ws, size_t ws_size,
                              hipStream_t stream) {
    const float* fm   = (const float*)d_in[0];
    const float* rois = (const float*)d_in[1];
    float* out        = (float*)d_out;
    ROIPoolingLayer_62079457296467_kernel<<<NBLK, 256, 0, stream>>>(fm, rois, out);
}